// Round 1
// 1653.964 us; speedup vs baseline: 1.2291x; 1.2291x over previous
//
#include <hip/hip_runtime.h>
#include <cmath>

#define BB 16
#define LL 512
#define FEAT 512
#define NLAB 4096
#define LLAB 32
#define EE 300
#define KK 4
#define TCONV (LLAB - KK + 1)  // 29

typedef __bf16 bf16x8 __attribute__((ext_vector_type(8)));
typedef __bf16 bf16x4 __attribute__((ext_vector_type(4)));
typedef float f32x4 __attribute__((ext_vector_type(4)));

// 16B global->LDS DMA (wave-uniform LDS base + lane*16; global addr is per-lane)
__device__ __forceinline__ void gl2lds16(const void* g, void* l) {
    __builtin_amdgcn_global_load_lds((const __attribute__((address_space(1))) unsigned int*)g,
                                     (__attribute__((address_space(3))) unsigned int*)l,
                                     16, 0, 0);
}

// ---------------------------------------------------------------------------
// Kernel 0: weight prep. conv_w [f][e][k] fp32 -> pre-split + PRE-SWIZZLED
// tiled bf16 layout consumed verbatim by global_load_lds:
//   chunk idx = ((fb*10 + ko)*128 + c)*4 + t   (16B chunks)
//   content   = elements e = ko*32 + q*8 + j,  q = t ^ ((c>>1)&3)   (XOR swizzle)
//   c = k*32 + fj  (f = fb*32 + fj, k = c>>5), e >= 300 zero-padded.
// Also zeroes the 16B zbuf used for A-tile edge padding.
// ---------------------------------------------------------------------------
__global__ __launch_bounds__(256) void wprep(const float* __restrict__ conv_w,
                                             __bf16* __restrict__ wB_hi,
                                             __bf16* __restrict__ wB_lo,
                                             float* __restrict__ zbuf) {
    const int idx = blockIdx.x * 256 + threadIdx.x;   // 0..81919
    if (idx == 0) { zbuf[0] = 0.f; zbuf[1] = 0.f; zbuf[2] = 0.f; zbuf[3] = 0.f; }
    const int fb  = idx / 5120;
    const int rem = idx - fb * 5120;
    const int ko  = rem >> 9;
    const int r2  = rem & 511;
    const int c   = r2 >> 2;
    const int t   = r2 & 3;
    const int q   = t ^ ((c >> 1) & 3);
    const int f   = fb * 32 + (c & 31);
    const int k   = c >> 5;
    bf16x8 h, l;
#pragma unroll
    for (int j = 0; j < 8; ++j) {
        const int e = ko * 32 + q * 8 + j;
        const float v = (e < 300) ? conv_w[((size_t)f * 300 + e) * 4 + k] : 0.f;
        h[j] = (__bf16)v;
        l[j] = (__bf16)(v - (float)h[j]);
    }
    *(bf16x8*)(wB_hi + (size_t)idx * 8) = h;
    *(bf16x8*)(wB_lo + (size_t)idx * 8) = l;
}

// ---------------------------------------------------------------------------
// Kernel 1: implicit-GEMM conv + shift-add(k) + bias + relu + maxpool -> lr0
// Grid: (16 fb, 1024 nb). Block: 256 thr = 4 waves. Tile 128x128, K-step 32.
// A staged fp32 via global_load_lds, XOR-swizzled (chunk ^= row&7, row=128B);
// B staged pre-split/pre-swizzled bf16 via global_load_lds (slot ^= (row>>1)&3).
// 2-phase double-buffered pipeline: stage(next) -> ds_read+MFMA(cur) -> barrier.
// A hi/lo split done in registers at frag load. 3-pass split-bf16 MFMA.
// Frag layouts (verified m89/m91): A/B row/col=lane&15, k=quad*8+j;
//                                  D col=lane&15, row=quad*4+reg.
// ---------------------------------------------------------------------------
__global__ __launch_bounds__(256) void conv_mfma(const float* __restrict__ label_reps,
                                                 const __bf16* __restrict__ wB_hi,
                                                 const __bf16* __restrict__ wB_lo,
                                                 const float* __restrict__ zbuf,
                                                 const float* __restrict__ conv_b,
                                                 float* __restrict__ lr0) {
    const int fb = blockIdx.x;   // 0..15
    const int nb = blockIdx.y;   // 0..1023
    const int tid = threadIdx.x;
    const int wave = tid >> 6;
    const int lane = tid & 63;
    const int quad = lane >> 4;
    const int l16  = lane & 15;

    // per buf: A fp32 swz [0,16384) = [128 rows][8 chunks16B],
    //          Bh [16384,24576), Bl [24576,32768) = [128 rows][4 slots16B]
    __shared__ __align__(16) char lds[2][32768];

    // ---- per-thread staging descriptors (loop-invariant) ----
    const float* srcA[4];
    int offA[4], cp4[4];
#pragma unroll
    for (int rnd = 0; rnd < 4; ++rnd) {
        const int ch  = rnd * 256 + tid;      // 0..1023
        const int row = ch >> 3;
        const int t   = ch & 7;
        const int cp  = t ^ (row & 7);        // e-chunk (XOR pre-swizzle of source)
        srcA[rnd] = label_reps + (size_t)(nb * 128 + row) * 300 + cp * 4;
        offA[rnd] = ch * 16;
        cp4[rnd]  = cp * 4;
    }
    const char* bh_g = (const char*)wB_hi + (size_t)fb * 10 * 8192;
    const char* bl_g = (const char*)wB_lo + (size_t)fb * 10 * 8192;

    f32x4 acc[2][8];   // [ri][cj]; cj: k = cj>>1, fhalf = cj&1
#pragma unroll
    for (int ri = 0; ri < 2; ++ri)
#pragma unroll
        for (int cj = 0; cj < 8; ++cj) acc[ri][cj] = (f32x4){0.f, 0.f, 0.f, 0.f};

    auto stage = [&](int buf, int ko) {
        char* base = &lds[buf][0];
        const int e0 = ko * 32;
#pragma unroll
        for (int rnd = 0; rnd < 4; ++rnd) {
            // only the last K-tile (ko=9) has e>=300 chunks; 300-288=12 -> chunk-exact
            const float* s = (e0 + cp4[rnd] < 300) ? (srcA[rnd] + e0) : zbuf;
            gl2lds16(s, base + offA[rnd]);
        }
        const char* bh = bh_g + (size_t)ko * 8192;
        const char* bl = bl_g + (size_t)ko * 8192;
#pragma unroll
        for (int rnd = 0; rnd < 2; ++rnd) {
            const int o = rnd * 4096 + tid * 16;
            gl2lds16(bh + o, base + 16384 + o);
            gl2lds16(bl + o, base + 24576 + o);
        }
    };

    stage(0, 0);
    __syncthreads();

    const int s3 = l16 & 7;                    // == arow&7 (arow base multiple of 16)
    const int bq = quad ^ ((l16 >> 1) & 3);    // == quad ^ ((brow>>1)&3)

    for (int ko = 0; ko < 10; ++ko) {
        const int buf = ko & 1;
        if (ko < 9) stage(buf ^ 1, ko + 1);    // prefetch stays in flight over MFMA
        const char* base = &lds[buf][0];

        // ---- A frags: 2x ds_read_b128 fp32 per ri, split hi/lo in regs ----
        bf16x8 ah[2], al[2];
#pragma unroll
        for (int ri = 0; ri < 2; ++ri) {
            const int arow = wave * 32 + ri * 16 + l16;
            const char* ap = base + arow * 128;
            const f32x4 v0 = *(const f32x4*)(ap + (((quad * 2) ^ s3) * 16));
            const f32x4 v1 = *(const f32x4*)(ap + (((quad * 2 + 1) ^ s3) * 16));
            bf16x8 h, l;
#pragma unroll
            for (int j = 0; j < 4; ++j) {
                h[j]     = (__bf16)v0[j]; l[j]     = (__bf16)(v0[j] - (float)h[j]);
                h[4 + j] = (__bf16)v1[j]; l[4 + j] = (__bf16)(v1[j] - (float)h[4 + j]);
            }
            ah[ri] = h; al[ri] = l;
        }
        // ---- MFMA: 8 cj x 2 ri x 3 passes ----
#pragma unroll
        for (int cj = 0; cj < 8; ++cj) {
            const int brow = cj * 16 + l16;
            const bf16x8 bh = *(const bf16x8*)(base + 16384 + brow * 64 + bq * 16);
            const bf16x8 bl = *(const bf16x8*)(base + 24576 + brow * 64 + bq * 16);
#pragma unroll
            for (int ri = 0; ri < 2; ++ri) {
                acc[ri][cj] = __builtin_amdgcn_mfma_f32_16x16x32_bf16(ah[ri], bh, acc[ri][cj], 0, 0, 0);
                acc[ri][cj] = __builtin_amdgcn_mfma_f32_16x16x32_bf16(ah[ri], bl, acc[ri][cj], 0, 0, 0);
                acc[ri][cj] = __builtin_amdgcn_mfma_f32_16x16x32_bf16(al[ri], bh, acc[ri][cj], 0, 0, 0);
            }
        }
        __syncthreads();
    }
    // ---- epilogue: h[t][f] = sum_k C[t+k][k], then max_t, +bias, relu ----
    const int label = nb * 4 + wave;
#pragma unroll
    for (int fh = 0; fh < 2; ++fh) {
        float m = -INFINITY;
#pragma unroll
        for (int t = 0; t < TCONV; ++t) {
            float loc = 0.f;
#pragma unroll
            for (int k = 0; k < KK; ++k) {
                const int r = t + k;                 // 0..31
                const float v = acc[r >> 4][k * 2 + fh][r & 3];
                loc += (((r >> 2) & 3) == quad) ? v : 0.f;
            }
            loc += __shfl_xor(loc, 16);
            loc += __shfl_xor(loc, 32);
            m = fmaxf(m, loc);
        }
        if (quad == 0) {
            const int f = fb * 32 + fh * 16 + l16;
            lr0[(size_t)label * FEAT + f] = fmaxf(m + conv_b[f], 0.f);
        }
    }
}

// ---------------------------------------------------------------------------
// Kernel 2: lr = lr0 @ lin_w^T + lin_b, epilogue split -> lr_hi/lr_lo (bf16)
// ---------------------------------------------------------------------------
__global__ __launch_bounds__(256) void linear_kernel(const float* __restrict__ lr0,
                                                     const float* __restrict__ lin_w,
                                                     const float* __restrict__ lin_b,
                                                     __bf16* __restrict__ lr_hi,
                                                     __bf16* __restrict__ lr_lo) {
    const int m0 = blockIdx.x * 64;
    const int i0 = blockIdx.y * 64;
    const int tid = threadIdx.x;
    const int tx = tid & 15;
    const int ty = tid >> 4;
    __shared__ float As[16][65];
    __shared__ float Bs[16][65];
    float acc[4][4] = {};

    for (int k0 = 0; k0 < 512; k0 += 16) {
        const int k = tid & 15, m = tid >> 4;
#pragma unroll
        for (int p = 0; p < 4; ++p)
            As[k][m + p*16] = lr0[(size_t)(m0 + m + p*16) * 512 + k0 + k];
#pragma unroll
        for (int p = 0; p < 4; ++p)
            Bs[k][m + p*16] = lin_w[(size_t)(i0 + m + p*16) * 512 + k0 + k];
        __syncthreads();
#pragma unroll
        for (int kk = 0; kk < 16; ++kk) {
            float a[4], b[4];
#pragma unroll
            for (int r = 0; r < 4; ++r) { a[r] = As[kk][ty*4 + r]; b[r] = Bs[kk][tx*4 + r]; }
#pragma unroll
            for (int ar = 0; ar < 4; ++ar)
#pragma unroll
                for (int br = 0; br < 4; ++br)
                    acc[ar][br] = fmaf(a[ar], b[br], acc[ar][br]);
        }
        __syncthreads();
    }
#pragma unroll
    for (int ar = 0; ar < 4; ++ar) {
        const int row = m0 + ty*4 + ar;
        const int col = i0 + tx*4;
#pragma unroll
        for (int br = 0; br < 4; ++br) {
            float v = acc[ar][br] + lin_b[col + br];
            __bf16 h = (__bf16)v;
            lr_hi[(size_t)row * 512 + col + br] = h;
            lr_lo[(size_t)row * 512 + col + br] = (__bf16)(v - (float)h);
        }
    }
}

// ---------------------------------------------------------------------------
// Kernel 2b: split x -> x_hi/x_lo (bf16 [b][l][f]) + xT (bf16 [b][f][l])
// ---------------------------------------------------------------------------
__global__ __launch_bounds__(256) void split_x(const float* __restrict__ x,
                                               __bf16* __restrict__ x_hi,
                                               __bf16* __restrict__ x_lo,
                                               __bf16* __restrict__ xT) {
    const int b  = blockIdx.z;
    const int l0 = blockIdx.y * 64;
    const int f0 = blockIdx.x * 64;
    const int tid = threadIdx.x;
    __shared__ __bf16 tile[64][65];
    const int j = tid & 63;
#pragma unroll
    for (int s = 0; s < 16; ++s) {
        const int rr = (tid >> 6) + s * 4;
        const size_t o = ((size_t)(b * 512 + l0 + rr)) * 512 + f0 + j;
        float v = x[o];
        __bf16 h = (__bf16)v;
        x_hi[o] = h;
        x_lo[o] = (__bf16)(v - (float)h);
        tile[rr][j] = h;
    }
    __syncthreads();
#pragma unroll
    for (int s = 0; s < 16; ++s) {
        const int ff = (tid >> 6) + s * 4;
        xT[((size_t)(b * 512 + f0 + ff)) * 512 + l0 + j] = tile[j][ff];
    }
}

// ---------------------------------------------------------------------------
// Kernel 3: MFMA flash attention (unchanged, verified).
// ---------------------------------------------------------------------------
#define LT 64

__global__ __launch_bounds__(256) void attention_mfma(const __bf16* __restrict__ x_hi,
                                                      const __bf16* __restrict__ x_lo,
                                                      const __bf16* __restrict__ xT,
                                                      const __bf16* __restrict__ lr_hi,
                                                      const __bf16* __restrict__ lr_lo,
                                                      float* __restrict__ out) {
    const int b  = blockIdx.y;
    const int n0 = blockIdx.x * 16;
    const int tid  = threadIdx.x;
    const int wave = tid >> 6;
    const int lane = tid & 63;
    const int quad = lane >> 4;
    const int l16  = lane & 15;

    __shared__ float m_run[16];
    __shared__ float d_run[16];
    __shared__ float wavemax[4][16];
    __shared__ float wavesum[4][16];
    __shared__ float Ps[16][LT + 4];

    if (tid < 16) { m_run[tid] = -INFINITY; d_run[tid] = 0.f; }
    __syncthreads();

    f32x4 oacc[8];
#pragma unroll
    for (int fs = 0; fs < 8; ++fs) oacc[fs] = (f32x4){0.f, 0.f, 0.f, 0.f};

    const __bf16* lrh = lr_hi + (size_t)(n0 + l16) * FEAT + quad * 8;
    const __bf16* lrl = lr_lo + (size_t)(n0 + l16) * FEAT + quad * 8;

    for (int lt = 0; lt < LL; lt += LT) {
        const int lbase = lt + wave * 16;
        f32x4 s = (f32x4){0.f, 0.f, 0.f, 0.f};
        const __bf16* xh = x_hi + ((size_t)(b * LL + lbase + l16)) * FEAT + quad * 8;
        const __bf16* xl = x_lo + ((size_t)(b * LL + lbase + l16)) * FEAT + quad * 8;
#pragma unroll
        for (int k0 = 0; k0 < FEAT; k0 += 32) {
            const bf16x8 ah = *(const bf16x8*)(lrh + k0);
            const bf16x8 al = *(const bf16x8*)(lrl + k0);
            const bf16x8 bh = *(const bf16x8*)(xh + k0);
            const bf16x8 bl = *(const bf16x8*)(xl + k0);
            s = __builtin_amdgcn_mfma_f32_16x16x32_bf16(ah, bh, s, 0, 0, 0);
            s = __builtin_amdgcn_mfma_f32_16x16x32_bf16(ah, bl, s, 0, 0, 0);
            s = __builtin_amdgcn_mfma_f32_16x16x32_bf16(al, bh, s, 0, 0, 0);
        }
        float rmax[4];
#pragma unroll
        for (int r = 0; r < 4; ++r) {
            float v = s[r];
            v = fmaxf(v, __shfl_xor(v, 1));
            v = fmaxf(v, __shfl_xor(v, 2));
            v = fmaxf(v, __shfl_xor(v, 4));
            v = fmaxf(v, __shfl_xor(v, 8));
            rmax[r] = v;
        }
        if (l16 == 0) {
#pragma unroll
            for (int r = 0; r < 4; ++r) wavemax[wave][quad * 4 + r] = rmax[r];
        }
        __syncthreads();
        float mnew[4], alpha[4], p[4];
#pragma unroll
        for (int r = 0; r < 4; ++r) {
            const int n = quad * 4 + r;
            float tm = fmaxf(fmaxf(wavemax[0][n], wavemax[1][n]),
                             fmaxf(wavemax[2][n], wavemax[3][n]));
            float mo = m_run[n];
            mnew[r]  = fmaxf(mo, tm);
            alpha[r] = __expf(mo - mnew[r]);
            p[r]     = __expf(s[r] - mnew[r]);
            float ps = p[r];
            ps += __shfl_xor(ps, 1);
            ps += __shfl_xor(ps, 2);
            ps += __shfl_xor(ps, 4);
            ps += __shfl_xor(ps, 8);
            if (l16 == 0) wavesum[wave][n] = ps;
            Ps[n][wave * 16 + l16] = p[r];
        }
        __syncthreads();
        if (wave == 0 && l16 == 0) {
#pragma unroll
            for (int r = 0; r < 4; ++r) {
                const int n = quad * 4 + r;
                float sum4 = wavesum[0][n] + wavesum[1][n] + wavesum[2][n] + wavesum[3][n];
                d_run[n] = d_run[n] * alpha[r] + sum4;
                m_run[n] = mnew[r];
            }
        }
        __syncthreads();
#pragma unroll
        for (int fs = 0; fs < 8; ++fs)
#pragma unroll
            for (int r = 0; r < 4; ++r) oacc[fs][r] *= alpha[r];

        bf16x8 ap[2];
#pragma unroll
        for (int kb = 0; kb < 2; ++kb) {
            const float* srcp = &Ps[l16][kb * 32 + quad * 8];
            const float4 v0 = *(const float4*)(srcp);
            const float4 v1 = *(const float4*)(srcp + 4);
            bf16x8 t;
            t[0] = (__bf16)v0.x; t[1] = (__bf16)v0.y; t[2] = (__bf16)v0.z; t[3] = (__bf16)v0.w;
            t[4] = (__bf16)v1.x; t[5] = (__bf16)v1.y; t[6] = (__bf16)v1.z; t[7] = (__bf16)v1.w;
            ap[kb] = t;
        }
        const __bf16* xtb = xT + ((size_t)(b * FEAT + wave * 128 + l16)) * LL + lt + quad * 8;
#pragma unroll
        for (int fs = 0; fs < 8; ++fs) {
#pragma unroll
            for (int kb = 0; kb < 2; ++kb) {
                const bf16x8 bfrag = *(const bf16x8*)(xtb + (size_t)fs * 16 * LL + kb * 32);
                oacc[fs] = __builtin_amdgcn_mfma_f32_16x16x32_bf16(ap[kb], bfrag, oacc[fs], 0, 0, 0);
            }
        }
    }
    float dinv[4];
#pragma unroll
    for (int r = 0; r < 4; ++r) dinv[r] = 1.0f / d_run[quad * 4 + r];
#pragma unroll
    for (int fs = 0; fs < 8; ++fs) {
#pragma unroll
        for (int r = 0; r < 4; ++r) {
            const int n = n0 + quad * 4 + r;
            const int f = wave * 128 + fs * 16 + l16;
            out[((size_t)(b * NLAB + n)) * FEAT + f] = oacc[fs][r] * dinv[r];
        }
    }
}

// ---------------------------------------------------------------------------
// Workspace layout (float-slot offsets), peak ~32 MB:
//   [0        .. 1048576)  lr_hi   (4096*512 bf16)
//   [1048576  .. 2097152)  lr_lo
//   [2097152  .. 2424832)  wB_hi   (16*10*128*4 chunks bf16, dead after conv)
//   [2424832  .. 2752512)  wB_lo   (dead after conv_mfma)
//   [2752512  .. 2752516)  zbuf    (16B zeros, dead after conv_mfma)
//   [2752528  .. 4849680)  lr0     (fp32, dead after linear_kernel)
//   [2097152  .. 4194304)  x_hi    (written by split_x, after linear)
//   [4194304  .. 6291456)  x_lo
//   [6291456  .. 8388608)  xT
// ---------------------------------------------------------------------------
extern "C" void kernel_launch(void* const* d_in, const int* in_sizes, int n_in,
                              void* d_out, int out_size, void* d_ws, size_t ws_size,
                              hipStream_t stream) {
    const float* x          = (const float*)d_in[0];  // (16,512,512)
    const float* label_reps = (const float*)d_in[1];  // (4096,32,300)
    const float* conv_w     = (const float*)d_in[2];  // (512,300,4)
    const float* conv_b     = (const float*)d_in[3];  // (512,)
    const float* lin_w      = (const float*)d_in[4];  // (512,512)
    const float* lin_b      = (const float*)d_in[5];  // (512,)
    float* out = (float*)d_out;

    float* wsf = (float*)d_ws;
    __bf16* lr_hi = (__bf16*)(wsf);
    __bf16* lr_lo = (__bf16*)(wsf + 1048576);
    __bf16* wB_hi = (__bf16*)(wsf + 2097152);
    __bf16* wB_lo = (__bf16*)(wsf + 2424832);
    float*  zbuf  = wsf + 2752512;
    float*  lr0   = wsf + 2752528;
    __bf16* x_hi  = (__bf16*)(wsf + 2097152);   // aliases wB/zbuf/lr0 (dead by then)
    __bf16* x_lo  = (__bf16*)(wsf + 4194304);
    __bf16* xT    = (__bf16*)(wsf + 6291456);

    wprep<<<dim3(320), dim3(256), 0, stream>>>(conv_w, wB_hi, wB_lo, zbuf);
    conv_mfma<<<dim3(16, 1024), dim3(256), 0, stream>>>(label_reps, wB_hi, wB_lo, zbuf, conv_b, lr0);
    linear_kernel<<<dim3(64, 8), dim3(256), 0, stream>>>(lr0, lin_w, lin_b, lr_hi, lr_lo);
    split_x<<<dim3(8, 8, 16), dim3(256), 0, stream>>>(x, x_hi, x_lo, xT);
    attention_mfma<<<dim3(NLAB / 16, BB), dim3(256), 0, stream>>>(x_hi, x_lo, xT, lr_hi, lr_lo, out);
}

// Round 2
// 1562.822 us; speedup vs baseline: 1.3008x; 1.0583x over previous
//
#include <hip/hip_runtime.h>
#include <cmath>

#define BB 16
#define LL 512
#define FEAT 512
#define NLAB 4096
#define LLAB 32
#define EE 300
#define KK 4
#define TCONV (LLAB - KK + 1)  // 29

typedef __bf16 bf16x8 __attribute__((ext_vector_type(8)));
typedef __bf16 bf16x4 __attribute__((ext_vector_type(4)));
typedef float f32x4 __attribute__((ext_vector_type(4)));

// 16B global->LDS DMA (wave-uniform LDS base + lane*16; global addr is per-lane)
__device__ __forceinline__ void gl2lds16(const void* g, void* l) {
    __builtin_amdgcn_global_load_lds((const __attribute__((address_space(1))) unsigned int*)g,
                                     (__attribute__((address_space(3))) unsigned int*)l,
                                     16, 0, 0);
}

// ---------------------------------------------------------------------------
// Kernel 0: weight prep. conv_w [f][e][k] fp32 -> pre-split + PRE-SWIZZLED
// tiled bf16 layout consumed verbatim by global_load_lds:
//   chunk idx = ((fb*10 + ko)*128 + c)*4 + t   (16B chunks)
//   content   = elements e = ko*32 + q*8 + j,  q = t ^ ((c>>1)&3)   (XOR swizzle)
//   c = k*32 + fj  (f = fb*32 + fj, k = c>>5), e >= 300 zero-padded.
// Also zeroes the 16B zbuf used for A-tile edge padding.
// ---------------------------------------------------------------------------
__global__ __launch_bounds__(256) void wprep(const float* __restrict__ conv_w,
                                             __bf16* __restrict__ wB_hi,
                                             __bf16* __restrict__ wB_lo,
                                             float* __restrict__ zbuf) {
    const int idx = blockIdx.x * 256 + threadIdx.x;   // 0..81919
    if (idx == 0) { zbuf[0] = 0.f; zbuf[1] = 0.f; zbuf[2] = 0.f; zbuf[3] = 0.f; }
    const int fb  = idx / 5120;
    const int rem = idx - fb * 5120;
    const int ko  = rem >> 9;
    const int r2  = rem & 511;
    const int c   = r2 >> 2;
    const int t   = r2 & 3;
    const int q   = t ^ ((c >> 1) & 3);
    const int f   = fb * 32 + (c & 31);
    const int k   = c >> 5;
    bf16x8 h, l;
#pragma unroll
    for (int j = 0; j < 8; ++j) {
        const int e = ko * 32 + q * 8 + j;
        const float v = (e < 300) ? conv_w[((size_t)f * 300 + e) * 4 + k] : 0.f;
        h[j] = (__bf16)v;
        l[j] = (__bf16)(v - (float)h[j]);
    }
    *(bf16x8*)(wB_hi + (size_t)idx * 8) = h;
    *(bf16x8*)(wB_lo + (size_t)idx * 8) = l;
}

// ---------------------------------------------------------------------------
// Kernel 1: implicit-GEMM conv + shift-add(k) + bias + relu + maxpool -> lr0
// (unchanged from round 1 — verified)
// ---------------------------------------------------------------------------
__global__ __launch_bounds__(256) void conv_mfma(const float* __restrict__ label_reps,
                                                 const __bf16* __restrict__ wB_hi,
                                                 const __bf16* __restrict__ wB_lo,
                                                 const float* __restrict__ zbuf,
                                                 const float* __restrict__ conv_b,
                                                 float* __restrict__ lr0) {
    const int fb = blockIdx.x;   // 0..15
    const int nb = blockIdx.y;   // 0..1023
    const int tid = threadIdx.x;
    const int wave = tid >> 6;
    const int lane = tid & 63;
    const int quad = lane >> 4;
    const int l16  = lane & 15;

    // per buf: A fp32 swz [0,16384) = [128 rows][8 chunks16B],
    //          Bh [16384,24576), Bl [24576,32768) = [128 rows][4 slots16B]
    __shared__ __align__(16) char lds[2][32768];

    // ---- per-thread staging descriptors (loop-invariant) ----
    const float* srcA[4];
    int offA[4], cp4[4];
#pragma unroll
    for (int rnd = 0; rnd < 4; ++rnd) {
        const int ch  = rnd * 256 + tid;      // 0..1023
        const int row = ch >> 3;
        const int t   = ch & 7;
        const int cp  = t ^ (row & 7);        // e-chunk (XOR pre-swizzle of source)
        srcA[rnd] = label_reps + (size_t)(nb * 128 + row) * 300 + cp * 4;
        offA[rnd] = ch * 16;
        cp4[rnd]  = cp * 4;
    }
    const char* bh_g = (const char*)wB_hi + (size_t)fb * 10 * 8192;
    const char* bl_g = (const char*)wB_lo + (size_t)fb * 10 * 8192;

    f32x4 acc[2][8];   // [ri][cj]; cj: k = cj>>1, fhalf = cj&1
#pragma unroll
    for (int ri = 0; ri < 2; ++ri)
#pragma unroll
        for (int cj = 0; cj < 8; ++cj) acc[ri][cj] = (f32x4){0.f, 0.f, 0.f, 0.f};

    auto stage = [&](int buf, int ko) {
        char* base = &lds[buf][0];
        const int e0 = ko * 32;
#pragma unroll
        for (int rnd = 0; rnd < 4; ++rnd) {
            // only the last K-tile (ko=9) has e>=300 chunks; 300-288=12 -> chunk-exact
            const float* s = (e0 + cp4[rnd] < 300) ? (srcA[rnd] + e0) : zbuf;
            gl2lds16(s, base + offA[rnd]);
        }
        const char* bh = bh_g + (size_t)ko * 8192;
        const char* bl = bl_g + (size_t)ko * 8192;
#pragma unroll
        for (int rnd = 0; rnd < 2; ++rnd) {
            const int o = rnd * 4096 + tid * 16;
            gl2lds16(bh + o, base + 16384 + o);
            gl2lds16(bl + o, base + 24576 + o);
        }
    };

    stage(0, 0);
    __syncthreads();

    const int s3 = l16 & 7;                    // == arow&7 (arow base multiple of 16)
    const int bq = quad ^ ((l16 >> 1) & 3);    // == quad ^ ((brow>>1)&3)

    for (int ko = 0; ko < 10; ++ko) {
        const int buf = ko & 1;
        if (ko < 9) stage(buf ^ 1, ko + 1);    // prefetch stays in flight over MFMA
        const char* base = &lds[buf][0];

        // ---- A frags: 2x ds_read_b128 fp32 per ri, split hi/lo in regs ----
        bf16x8 ah[2], al[2];
#pragma unroll
        for (int ri = 0; ri < 2; ++ri) {
            const int arow = wave * 32 + ri * 16 + l16;
            const char* ap = base + arow * 128;
            const f32x4 v0 = *(const f32x4*)(ap + (((quad * 2) ^ s3) * 16));
            const f32x4 v1 = *(const f32x4*)(ap + (((quad * 2 + 1) ^ s3) * 16));
            bf16x8 h, l;
#pragma unroll
            for (int j = 0; j < 4; ++j) {
                h[j]     = (__bf16)v0[j]; l[j]     = (__bf16)(v0[j] - (float)h[j]);
                h[4 + j] = (__bf16)v1[j]; l[4 + j] = (__bf16)(v1[j] - (float)h[4 + j]);
            }
            ah[ri] = h; al[ri] = l;
        }
        // ---- MFMA: 8 cj x 2 ri x 3 passes ----
#pragma unroll
        for (int cj = 0; cj < 8; ++cj) {
            const int brow = cj * 16 + l16;
            const bf16x8 bh = *(const bf16x8*)(base + 16384 + brow * 64 + bq * 16);
            const bf16x8 bl = *(const bf16x8*)(base + 24576 + brow * 64 + bq * 16);
#pragma unroll
            for (int ri = 0; ri < 2; ++ri) {
                acc[ri][cj] = __builtin_amdgcn_mfma_f32_16x16x32_bf16(ah[ri], bh, acc[ri][cj], 0, 0, 0);
                acc[ri][cj] = __builtin_amdgcn_mfma_f32_16x16x32_bf16(ah[ri], bl, acc[ri][cj], 0, 0, 0);
                acc[ri][cj] = __builtin_amdgcn_mfma_f32_16x16x32_bf16(al[ri], bh, acc[ri][cj], 0, 0, 0);
            }
        }
        __syncthreads();
    }
    // ---- epilogue: h[t][f] = sum_k C[t+k][k], then max_t, +bias, relu ----
    const int label = nb * 4 + wave;
#pragma unroll
    for (int fh = 0; fh < 2; ++fh) {
        float m = -INFINITY;
#pragma unroll
        for (int t = 0; t < TCONV; ++t) {
            float loc = 0.f;
#pragma unroll
            for (int k = 0; k < KK; ++k) {
                const int r = t + k;                 // 0..31
                const float v = acc[r >> 4][k * 2 + fh][r & 3];
                loc += (((r >> 2) & 3) == quad) ? v : 0.f;
            }
            loc += __shfl_xor(loc, 16);
            loc += __shfl_xor(loc, 32);
            m = fmaxf(m, loc);
        }
        if (quad == 0) {
            const int f = fb * 32 + fh * 16 + l16;
            lr0[(size_t)label * FEAT + f] = fmaxf(m + conv_b[f], 0.f);
        }
    }
}

// ---------------------------------------------------------------------------
// Kernel 2: lr = lr0 @ lin_w^T + lin_b, epilogue split -> lr_hi/lr_lo (bf16)
// ---------------------------------------------------------------------------
__global__ __launch_bounds__(256) void linear_kernel(const float* __restrict__ lr0,
                                                     const float* __restrict__ lin_w,
                                                     const float* __restrict__ lin_b,
                                                     __bf16* __restrict__ lr_hi,
                                                     __bf16* __restrict__ lr_lo) {
    const int m0 = blockIdx.x * 64;
    const int i0 = blockIdx.y * 64;
    const int tid = threadIdx.x;
    const int tx = tid & 15;
    const int ty = tid >> 4;
    __shared__ float As[16][65];
    __shared__ float Bs[16][65];
    float acc[4][4] = {};

    for (int k0 = 0; k0 < 512; k0 += 16) {
        const int k = tid & 15, m = tid >> 4;
#pragma unroll
        for (int p = 0; p < 4; ++p)
            As[k][m + p*16] = lr0[(size_t)(m0 + m + p*16) * 512 + k0 + k];
#pragma unroll
        for (int p = 0; p < 4; ++p)
            Bs[k][m + p*16] = lin_w[(size_t)(i0 + m + p*16) * 512 + k0 + k];
        __syncthreads();
#pragma unroll
        for (int kk = 0; kk < 16; ++kk) {
            float a[4], b[4];
#pragma unroll
            for (int r = 0; r < 4; ++r) { a[r] = As[kk][ty*4 + r]; b[r] = Bs[kk][tx*4 + r]; }
#pragma unroll
            for (int ar = 0; ar < 4; ++ar)
#pragma unroll
                for (int br = 0; br < 4; ++br)
                    acc[ar][br] = fmaf(a[ar], b[br], acc[ar][br]);
        }
        __syncthreads();
    }
#pragma unroll
    for (int ar = 0; ar < 4; ++ar) {
        const int row = m0 + ty*4 + ar;
        const int col = i0 + tx*4;
#pragma unroll
        for (int br = 0; br < 4; ++br) {
            float v = acc[ar][br] + lin_b[col + br];
            __bf16 h = (__bf16)v;
            lr_hi[(size_t)row * 512 + col + br] = h;
            lr_lo[(size_t)row * 512 + col + br] = (__bf16)(v - (float)h);
        }
    }
}

// ---------------------------------------------------------------------------
// Kernel 2b: split x -> x_hi/x_lo (bf16 [b][l][f]) + xT (bf16 [b][f][l])
// ---------------------------------------------------------------------------
__global__ __launch_bounds__(256) void split_x(const float* __restrict__ x,
                                               __bf16* __restrict__ x_hi,
                                               __bf16* __restrict__ x_lo,
                                               __bf16* __restrict__ xT) {
    const int b  = blockIdx.z;
    const int l0 = blockIdx.y * 64;
    const int f0 = blockIdx.x * 64;
    const int tid = threadIdx.x;
    __shared__ __bf16 tile[64][65];
    const int j = tid & 63;
#pragma unroll
    for (int s = 0; s < 16; ++s) {
        const int rr = (tid >> 6) + s * 4;
        const size_t o = ((size_t)(b * 512 + l0 + rr)) * 512 + f0 + j;
        float v = x[o];
        __bf16 h = (__bf16)v;
        x_hi[o] = h;
        x_lo[o] = (__bf16)(v - (float)h);
        tile[rr][j] = h;
    }
    __syncthreads();
#pragma unroll
    for (int s = 0; s < 16; ++s) {
        const int ff = (tid >> 6) + s * 4;
        xT[((size_t)(b * 512 + f0 + ff)) * 512 + l0 + j] = tile[j][ff];
    }
}

// ---------------------------------------------------------------------------
// Kernel 3: de-flashed attention. L=512 fits in registers: compute full S
// (16 n x 512 l per block; wave w owns l-quarter w*128), ONE softmax pass
// (2 barriers total), P -> bf16 LDS once, then PV.
// Frag layouts as verified: A row=lane&15, k=quad*8+j; D col=lane&15,
// row=quad*4+reg. QK: A=lr(n), B=x(l) -> S[n=quad*4+r][l=l16-based].
// PV: A=Ps(n rows), B=xT(f rows) -> out[n=quad*4+r][f=l16-based].
// ---------------------------------------------------------------------------
__global__ __launch_bounds__(256) void attention_mfma(const __bf16* __restrict__ x_hi,
                                                      const __bf16* __restrict__ x_lo,
                                                      const __bf16* __restrict__ xT,
                                                      const __bf16* __restrict__ lr_hi,
                                                      const __bf16* __restrict__ lr_lo,
                                                      float* __restrict__ out) {
    const int b  = blockIdx.y;
    const int n0 = blockIdx.x * 16;
    const int tid  = threadIdx.x;
    const int wave = tid >> 6;
    const int lane = tid & 63;
    const int quad = lane >> 4;
    const int l16  = lane & 15;

    __shared__ float wavemax[4][16];
    __shared__ float wavesum[4][16];
    // row stride 520 bf16 = 1040 B = 65 x 16B slots -> uniform bank spread
    __shared__ __align__(16) __bf16 Ps[16][520];

    // ---- phase A: full S, no barriers. k outer (lr frags hoisted), lt inner.
    f32x4 sacc[8];
#pragma unroll
    for (int lt = 0; lt < 8; ++lt) sacc[lt] = (f32x4){0.f, 0.f, 0.f, 0.f};

    const __bf16* lrh = lr_hi + (size_t)(n0 + l16) * FEAT + quad * 8;
    const __bf16* lrl = lr_lo + (size_t)(n0 + l16) * FEAT + quad * 8;
    const __bf16* xh0 = x_hi + ((size_t)(b * LL + wave * 128 + l16)) * FEAT + quad * 8;
    const __bf16* xl0 = x_lo + ((size_t)(b * LL + wave * 128 + l16)) * FEAT + quad * 8;

#pragma unroll 2
    for (int ks = 0; ks < 16; ++ks) {
        const int k0 = ks * 32;
        const bf16x8 ah = *(const bf16x8*)(lrh + k0);
        const bf16x8 al = *(const bf16x8*)(lrl + k0);
#pragma unroll
        for (int lt = 0; lt < 8; ++lt) {
            const bf16x8 bh = *(const bf16x8*)(xh0 + lt * 16 * FEAT + k0);
            const bf16x8 bl = *(const bf16x8*)(xl0 + lt * 16 * FEAT + k0);
            sacc[lt] = __builtin_amdgcn_mfma_f32_16x16x32_bf16(ah, bh, sacc[lt], 0, 0, 0);
            sacc[lt] = __builtin_amdgcn_mfma_f32_16x16x32_bf16(ah, bl, sacc[lt], 0, 0, 0);
            sacc[lt] = __builtin_amdgcn_mfma_f32_16x16x32_bf16(al, bh, sacc[lt], 0, 0, 0);
        }
    }

    // ---- phase B: one softmax pass. lane holds S[n=quad*4+r][l=wave*128+lt*16+l16]
    float m[4];
#pragma unroll
    for (int r = 0; r < 4; ++r) {
        float v = sacc[0][r];
#pragma unroll
        for (int lt = 1; lt < 8; ++lt) v = fmaxf(v, sacc[lt][r]);
        v = fmaxf(v, __shfl_xor(v, 1));
        v = fmaxf(v, __shfl_xor(v, 2));
        v = fmaxf(v, __shfl_xor(v, 4));
        v = fmaxf(v, __shfl_xor(v, 8));
        m[r] = v;
    }
    if (l16 == 0) {
#pragma unroll
        for (int r = 0; r < 4; ++r) wavemax[wave][quad * 4 + r] = m[r];
    }
    __syncthreads();
    float dsum[4];
#pragma unroll
    for (int r = 0; r < 4; ++r) {
        const int n = quad * 4 + r;
        m[r] = fmaxf(fmaxf(wavemax[0][n], wavemax[1][n]),
                     fmaxf(wavemax[2][n], wavemax[3][n]));
        float s = 0.f;
#pragma unroll
        for (int lt = 0; lt < 8; ++lt) {
            const float p = __expf(sacc[lt][r] - m[r]);
            s += p;
            Ps[n][wave * 128 + lt * 16 + l16] = (__bf16)p;
        }
        s += __shfl_xor(s, 1);
        s += __shfl_xor(s, 2);
        s += __shfl_xor(s, 4);
        s += __shfl_xor(s, 8);
        dsum[r] = s;
    }
    if (l16 == 0) {
#pragma unroll
        for (int r = 0; r < 4; ++r) wavesum[wave][quad * 4 + r] = dsum[r];
    }
    __syncthreads();
    float dinv[4];
#pragma unroll
    for (int r = 0; r < 4; ++r) {
        const int n = quad * 4 + r;
        dinv[r] = 1.0f / (wavesum[0][n] + wavesum[1][n] + wavesum[2][n] + wavesum[3][n]);
    }

    // ---- phase C: PV. wave owns f-range wave*128; A=Ps rows(n), B=xT rows(f).
    f32x4 oacc[8];
#pragma unroll
    for (int fs = 0; fs < 8; ++fs) oacc[fs] = (f32x4){0.f, 0.f, 0.f, 0.f};

    const __bf16* xtb = xT + ((size_t)(b * FEAT + wave * 128 + l16)) * LL + quad * 8;
#pragma unroll 2
    for (int kb = 0; kb < 16; ++kb) {
        const bf16x8 ap = *(const bf16x8*)&Ps[l16][kb * 32 + quad * 8];
#pragma unroll
        for (int fs = 0; fs < 8; ++fs) {
            const bf16x8 bfrag = *(const bf16x8*)(xtb + (size_t)fs * 16 * LL + kb * 32);
            oacc[fs] = __builtin_amdgcn_mfma_f32_16x16x32_bf16(ap, bfrag, oacc[fs], 0, 0, 0);
        }
    }

#pragma unroll
    for (int fs = 0; fs < 8; ++fs) {
#pragma unroll
        for (int r = 0; r < 4; ++r) {
            const int n = n0 + quad * 4 + r;
            const int f = wave * 128 + fs * 16 + l16;
            out[((size_t)(b * NLAB + n)) * FEAT + f] = oacc[fs][r] * dinv[r];
        }
    }
}

// ---------------------------------------------------------------------------
// Workspace layout (float-slot offsets), peak ~32 MB:
//   [0        .. 1048576)  lr_hi   (4096*512 bf16)
//   [1048576  .. 2097152)  lr_lo
//   [2097152  .. 2424832)  wB_hi   (16*10*128*4 chunks bf16, dead after conv)
//   [2424832  .. 2752512)  wB_lo   (dead after conv_mfma)
//   [2752512  .. 2752516)  zbuf    (16B zeros, dead after conv_mfma)
//   [2752528  .. 4849680)  lr0     (fp32, dead after linear_kernel)
//   [2097152  .. 4194304)  x_hi    (written by split_x, after linear)
//   [4194304  .. 6291456)  x_lo
//   [6291456  .. 8388608)  xT
// ---------------------------------------------------------------------------
extern "C" void kernel_launch(void* const* d_in, const int* in_sizes, int n_in,
                              void* d_out, int out_size, void* d_ws, size_t ws_size,
                              hipStream_t stream) {
    const float* x          = (const float*)d_in[0];  // (16,512,512)
    const float* label_reps = (const float*)d_in[1];  // (4096,32,300)
    const float* conv_w     = (const float*)d_in[2];  // (512,300,4)
    const float* conv_b     = (const float*)d_in[3];  // (512,)
    const float* lin_w      = (const float*)d_in[4];  // (512,512)
    const float* lin_b      = (const float*)d_in[5];  // (512,)
    float* out = (float*)d_out;

    float* wsf = (float*)d_ws;
    __bf16* lr_hi = (__bf16*)(wsf);
    __bf16* lr_lo = (__bf16*)(wsf + 1048576);
    __bf16* wB_hi = (__bf16*)(wsf + 2097152);
    __bf16* wB_lo = (__bf16*)(wsf + 2424832);
    float*  zbuf  = wsf + 2752512;
    float*  lr0   = wsf + 2752528;
    __bf16* x_hi  = (__bf16*)(wsf + 2097152);   // aliases wB/zbuf/lr0 (dead by then)
    __bf16* x_lo  = (__bf16*)(wsf + 4194304);
    __bf16* xT    = (__bf16*)(wsf + 6291456);

    wprep<<<dim3(320), dim3(256), 0, stream>>>(conv_w, wB_hi, wB_lo, zbuf);
    conv_mfma<<<dim3(16, 1024), dim3(256), 0, stream>>>(label_reps, wB_hi, wB_lo, zbuf, conv_b, lr0);
    linear_kernel<<<dim3(64, 8), dim3(256), 0, stream>>>(lr0, lin_w, lin_b, lr_hi, lr_lo);
    split_x<<<dim3(8, 8, 16), dim3(256), 0, stream>>>(x, x_hi, x_lo, xT);
    attention_mfma<<<dim3(NLAB / 16, BB), dim3(256), 0, stream>>>(x_hi, x_lo, xT, lr_hi, lr_lo, out);
}

// Round 3
// 1234.490 us; speedup vs baseline: 1.6467x; 1.2660x over previous
//
#include <hip/hip_runtime.h>
#include <cmath>

#define BB 16
#define LL 512
#define FEAT 512
#define NLAB 4096
#define LLAB 32
#define EE 300
#define KK 4
#define TCONV (LLAB - KK + 1)  // 29

typedef __bf16 bf16x8 __attribute__((ext_vector_type(8)));
typedef __bf16 bf16x4 __attribute__((ext_vector_type(4)));
typedef float f32x4 __attribute__((ext_vector_type(4)));

// 16B global->LDS DMA (wave-uniform LDS base + lane*16; global addr is per-lane)
__device__ __forceinline__ void gl2lds16(const void* g, void* l) {
    __builtin_amdgcn_global_load_lds((const __attribute__((address_space(1))) unsigned int*)g,
                                     (__attribute__((address_space(3))) unsigned int*)l,
                                     16, 0, 0);
}

// ---------------------------------------------------------------------------
// Kernel 0: weight prep. conv_w [f][e][k] fp32 -> pre-split + PRE-SWIZZLED
// tiled bf16 layout consumed verbatim by global_load_lds:
//   chunk idx = ((fb*10 + ko)*128 + c)*4 + t   (16B chunks)
//   content   = elements e = ko*32 + q*8 + j,  q = t ^ ((c>>1)&3)   (XOR swizzle)
//   c = k*32 + fj  (f = fb*32 + fj, k = c>>5), e >= 300 zero-padded.
// Also zeroes the 16B zbuf used for A-tile edge padding.
// ---------------------------------------------------------------------------
__global__ __launch_bounds__(256) void wprep(const float* __restrict__ conv_w,
                                             __bf16* __restrict__ wB_hi,
                                             __bf16* __restrict__ wB_lo,
                                             float* __restrict__ zbuf) {
    const int idx = blockIdx.x * 256 + threadIdx.x;   // 0..81919
    if (idx == 0) { zbuf[0] = 0.f; zbuf[1] = 0.f; zbuf[2] = 0.f; zbuf[3] = 0.f; }
    const int fb  = idx / 5120;
    const int rem = idx - fb * 5120;
    const int ko  = rem >> 9;
    const int r2  = rem & 511;
    const int c   = r2 >> 2;
    const int t   = r2 & 3;
    const int q   = t ^ ((c >> 1) & 3);
    const int f   = fb * 32 + (c & 31);
    const int k   = c >> 5;
    bf16x8 h, l;
#pragma unroll
    for (int j = 0; j < 8; ++j) {
        const int e = ko * 32 + q * 8 + j;
        const float v = (e < 300) ? conv_w[((size_t)f * 300 + e) * 4 + k] : 0.f;
        h[j] = (__bf16)v;
        l[j] = (__bf16)(v - (float)h[j]);
    }
    *(bf16x8*)(wB_hi + (size_t)idx * 8) = h;
    *(bf16x8*)(wB_lo + (size_t)idx * 8) = l;
}

// ---------------------------------------------------------------------------
// Kernel 1: implicit-GEMM conv + shift-add(k) + bias + relu + maxpool -> lr0
// (unchanged — verified)
// ---------------------------------------------------------------------------
__global__ __launch_bounds__(256) void conv_mfma(const float* __restrict__ label_reps,
                                                 const __bf16* __restrict__ wB_hi,
                                                 const __bf16* __restrict__ wB_lo,
                                                 const float* __restrict__ zbuf,
                                                 const float* __restrict__ conv_b,
                                                 float* __restrict__ lr0) {
    const int fb = blockIdx.x;   // 0..15
    const int nb = blockIdx.y;   // 0..1023
    const int tid = threadIdx.x;
    const int wave = tid >> 6;
    const int lane = tid & 63;
    const int quad = lane >> 4;
    const int l16  = lane & 15;

    // per buf: A fp32 swz [0,16384) = [128 rows][8 chunks16B],
    //          Bh [16384,24576), Bl [24576,32768) = [128 rows][4 slots16B]
    __shared__ __align__(16) char lds[2][32768];

    // ---- per-thread staging descriptors (loop-invariant) ----
    const float* srcA[4];
    int offA[4], cp4[4];
#pragma unroll
    for (int rnd = 0; rnd < 4; ++rnd) {
        const int ch  = rnd * 256 + tid;      // 0..1023
        const int row = ch >> 3;
        const int t   = ch & 7;
        const int cp  = t ^ (row & 7);        // e-chunk (XOR pre-swizzle of source)
        srcA[rnd] = label_reps + (size_t)(nb * 128 + row) * 300 + cp * 4;
        offA[rnd] = ch * 16;
        cp4[rnd]  = cp * 4;
    }
    const char* bh_g = (const char*)wB_hi + (size_t)fb * 10 * 8192;
    const char* bl_g = (const char*)wB_lo + (size_t)fb * 10 * 8192;

    f32x4 acc[2][8];   // [ri][cj]; cj: k = cj>>1, fhalf = cj&1
#pragma unroll
    for (int ri = 0; ri < 2; ++ri)
#pragma unroll
        for (int cj = 0; cj < 8; ++cj) acc[ri][cj] = (f32x4){0.f, 0.f, 0.f, 0.f};

    auto stage = [&](int buf, int ko) {
        char* base = &lds[buf][0];
        const int e0 = ko * 32;
#pragma unroll
        for (int rnd = 0; rnd < 4; ++rnd) {
            // only the last K-tile (ko=9) has e>=300 chunks; 300-288=12 -> chunk-exact
            const float* s = (e0 + cp4[rnd] < 300) ? (srcA[rnd] + e0) : zbuf;
            gl2lds16(s, base + offA[rnd]);
        }
        const char* bh = bh_g + (size_t)ko * 8192;
        const char* bl = bl_g + (size_t)ko * 8192;
#pragma unroll
        for (int rnd = 0; rnd < 2; ++rnd) {
            const int o = rnd * 4096 + tid * 16;
            gl2lds16(bh + o, base + 16384 + o);
            gl2lds16(bl + o, base + 24576 + o);
        }
    };

    stage(0, 0);
    __syncthreads();

    const int s3 = l16 & 7;                    // == arow&7 (arow base multiple of 16)
    const int bq = quad ^ ((l16 >> 1) & 3);    // == quad ^ ((brow>>1)&3)

    for (int ko = 0; ko < 10; ++ko) {
        const int buf = ko & 1;
        if (ko < 9) stage(buf ^ 1, ko + 1);    // prefetch stays in flight over MFMA
        const char* base = &lds[buf][0];

        // ---- A frags: 2x ds_read_b128 fp32 per ri, split hi/lo in regs ----
        bf16x8 ah[2], al[2];
#pragma unroll
        for (int ri = 0; ri < 2; ++ri) {
            const int arow = wave * 32 + ri * 16 + l16;
            const char* ap = base + arow * 128;
            const f32x4 v0 = *(const f32x4*)(ap + (((quad * 2) ^ s3) * 16));
            const f32x4 v1 = *(const f32x4*)(ap + (((quad * 2 + 1) ^ s3) * 16));
            bf16x8 h, l;
#pragma unroll
            for (int j = 0; j < 4; ++j) {
                h[j]     = (__bf16)v0[j]; l[j]     = (__bf16)(v0[j] - (float)h[j]);
                h[4 + j] = (__bf16)v1[j]; l[4 + j] = (__bf16)(v1[j] - (float)h[4 + j]);
            }
            ah[ri] = h; al[ri] = l;
        }
        // ---- MFMA: 8 cj x 2 ri x 3 passes ----
#pragma unroll
        for (int cj = 0; cj < 8; ++cj) {
            const int brow = cj * 16 + l16;
            const bf16x8 bh = *(const bf16x8*)(base + 16384 + brow * 64 + bq * 16);
            const bf16x8 bl = *(const bf16x8*)(base + 24576 + brow * 64 + bq * 16);
#pragma unroll
            for (int ri = 0; ri < 2; ++ri) {
                acc[ri][cj] = __builtin_amdgcn_mfma_f32_16x16x32_bf16(ah[ri], bh, acc[ri][cj], 0, 0, 0);
                acc[ri][cj] = __builtin_amdgcn_mfma_f32_16x16x32_bf16(ah[ri], bl, acc[ri][cj], 0, 0, 0);
                acc[ri][cj] = __builtin_amdgcn_mfma_f32_16x16x32_bf16(al[ri], bh, acc[ri][cj], 0, 0, 0);
            }
        }
        __syncthreads();
    }
    // ---- epilogue: h[t][f] = sum_k C[t+k][k], then max_t, +bias, relu ----
    const int label = nb * 4 + wave;
#pragma unroll
    for (int fh = 0; fh < 2; ++fh) {
        float m = -INFINITY;
#pragma unroll
        for (int t = 0; t < TCONV; ++t) {
            float loc = 0.f;
#pragma unroll
            for (int k = 0; k < KK; ++k) {
                const int r = t + k;                 // 0..31
                const float v = acc[r >> 4][k * 2 + fh][r & 3];
                loc += (((r >> 2) & 3) == quad) ? v : 0.f;
            }
            loc += __shfl_xor(loc, 16);
            loc += __shfl_xor(loc, 32);
            m = fmaxf(m, loc);
        }
        if (quad == 0) {
            const int f = fb * 32 + fh * 16 + l16;
            lr0[(size_t)label * FEAT + f] = fmaxf(m + conv_b[f], 0.f);
        }
    }
}

// ---------------------------------------------------------------------------
// Kernel 2: lr = lr0 @ lin_w^T + lin_b, epilogue split -> lr_hi/lr_lo (bf16)
// ---------------------------------------------------------------------------
__global__ __launch_bounds__(256) void linear_kernel(const float* __restrict__ lr0,
                                                     const float* __restrict__ lin_w,
                                                     const float* __restrict__ lin_b,
                                                     __bf16* __restrict__ lr_hi,
                                                     __bf16* __restrict__ lr_lo) {
    const int m0 = blockIdx.x * 64;
    const int i0 = blockIdx.y * 64;
    const int tid = threadIdx.x;
    const int tx = tid & 15;
    const int ty = tid >> 4;
    __shared__ float As[16][65];
    __shared__ float Bs[16][65];
    float acc[4][4] = {};

    for (int k0 = 0; k0 < 512; k0 += 16) {
        const int k = tid & 15, m = tid >> 4;
#pragma unroll
        for (int p = 0; p < 4; ++p)
            As[k][m + p*16] = lr0[(size_t)(m0 + m + p*16) * 512 + k0 + k];
#pragma unroll
        for (int p = 0; p < 4; ++p)
            Bs[k][m + p*16] = lin_w[(size_t)(i0 + m + p*16) * 512 + k0 + k];
        __syncthreads();
#pragma unroll
        for (int kk = 0; kk < 16; ++kk) {
            float a[4], b[4];
#pragma unroll
            for (int r = 0; r < 4; ++r) { a[r] = As[kk][ty*4 + r]; b[r] = Bs[kk][tx*4 + r]; }
#pragma unroll
            for (int ar = 0; ar < 4; ++ar)
#pragma unroll
                for (int br = 0; br < 4; ++br)
                    acc[ar][br] = fmaf(a[ar], b[br], acc[ar][br]);
        }
        __syncthreads();
    }
#pragma unroll
    for (int ar = 0; ar < 4; ++ar) {
        const int row = m0 + ty*4 + ar;
        const int col = i0 + tx*4;
#pragma unroll
        for (int br = 0; br < 4; ++br) {
            float v = acc[ar][br] + lin_b[col + br];
            __bf16 h = (__bf16)v;
            lr_hi[(size_t)row * 512 + col + br] = h;
            lr_lo[(size_t)row * 512 + col + br] = (__bf16)(v - (float)h);
        }
    }
}

// ---------------------------------------------------------------------------
// Kernel 2b: split x -> x_hi/x_lo (bf16 [b][l][f]) + xT (bf16 [b][f][l])
// ---------------------------------------------------------------------------
__global__ __launch_bounds__(256) void split_x(const float* __restrict__ x,
                                               __bf16* __restrict__ x_hi,
                                               __bf16* __restrict__ x_lo,
                                               __bf16* __restrict__ xT) {
    const int b  = blockIdx.z;
    const int l0 = blockIdx.y * 64;
    const int f0 = blockIdx.x * 64;
    const int tid = threadIdx.x;
    __shared__ __bf16 tile[64][65];
    const int j = tid & 63;
#pragma unroll
    for (int s = 0; s < 16; ++s) {
        const int rr = (tid >> 6) + s * 4;
        const size_t o = ((size_t)(b * 512 + l0 + rr)) * 512 + f0 + j;
        float v = x[o];
        __bf16 h = (__bf16)v;
        x_hi[o] = h;
        x_lo[o] = (__bf16)(v - (float)h);
        tile[rr][j] = h;
    }
    __syncthreads();
#pragma unroll
    for (int s = 0; s < 16; ++s) {
        const int ff = (tid >> 6) + s * 4;
        xT[((size_t)(b * 512 + f0 + ff)) * 512 + l0 + j] = tile[j][ff];
    }
}

// ---------------------------------------------------------------------------
// Kernel 3: de-flashed attention, 32 labels/block (2 n-tiles).
// Each wave owns l-quarter [wave*128, wave*128+128); S kept in registers
// (sacc[2][8]); every x fragment feeds 2 n-tiles (2x arithmetic intensity
// per global load vs 16n version). One softmax pass, 2 barriers.
// Frag layouts (verified): A row=lane&15, k=quad*8+j; D col=lane&15,
// row=quad*4+reg. QK: A=lr(n), B=x(l). PV: A=Ps(n rows), B=xT(f rows).
// ---------------------------------------------------------------------------
__global__ __launch_bounds__(256) void attention_mfma(const __bf16* __restrict__ x_hi,
                                                      const __bf16* __restrict__ x_lo,
                                                      const __bf16* __restrict__ xT,
                                                      const __bf16* __restrict__ lr_hi,
                                                      const __bf16* __restrict__ lr_lo,
                                                      float* __restrict__ out) {
    const int b  = blockIdx.y;
    const int n0 = blockIdx.x * 32;
    const int tid  = threadIdx.x;
    const int wave = tid >> 6;
    const int lane = tid & 63;
    const int quad = lane >> 4;
    const int l16  = lane & 15;

    __shared__ float wavemax[4][32];
    __shared__ float wavesum[4][32];
    // row stride 520 bf16 = 1040 B = 65 x 16B slots -> uniform bank spread
    __shared__ __align__(16) __bf16 Ps[32][520];

    // ---- phase A: full S for 2 n-tiles, no barriers. k outer, lt inner.
    f32x4 sacc[2][8];
#pragma unroll
    for (int nt = 0; nt < 2; ++nt)
#pragma unroll
        for (int lt = 0; lt < 8; ++lt) sacc[nt][lt] = (f32x4){0.f, 0.f, 0.f, 0.f};

    const __bf16* lrh0 = lr_hi + (size_t)(n0 + l16) * FEAT + quad * 8;
    const __bf16* lrl0 = lr_lo + (size_t)(n0 + l16) * FEAT + quad * 8;
    const __bf16* lrh1 = lrh0 + (size_t)16 * FEAT;
    const __bf16* lrl1 = lrl0 + (size_t)16 * FEAT;
    const __bf16* xh0 = x_hi + ((size_t)(b * LL + wave * 128 + l16)) * FEAT + quad * 8;
    const __bf16* xl0 = x_lo + ((size_t)(b * LL + wave * 128 + l16)) * FEAT + quad * 8;

#pragma unroll 2
    for (int ks = 0; ks < 16; ++ks) {
        const int k0 = ks * 32;
        const bf16x8 ah0 = *(const bf16x8*)(lrh0 + k0);
        const bf16x8 al0 = *(const bf16x8*)(lrl0 + k0);
        const bf16x8 ah1 = *(const bf16x8*)(lrh1 + k0);
        const bf16x8 al1 = *(const bf16x8*)(lrl1 + k0);
#pragma unroll
        for (int lt = 0; lt < 8; ++lt) {
            const bf16x8 bh = *(const bf16x8*)(xh0 + lt * 16 * FEAT + k0);
            const bf16x8 bl = *(const bf16x8*)(xl0 + lt * 16 * FEAT + k0);
            sacc[0][lt] = __builtin_amdgcn_mfma_f32_16x16x32_bf16(ah0, bh, sacc[0][lt], 0, 0, 0);
            sacc[0][lt] = __builtin_amdgcn_mfma_f32_16x16x32_bf16(ah0, bl, sacc[0][lt], 0, 0, 0);
            sacc[0][lt] = __builtin_amdgcn_mfma_f32_16x16x32_bf16(al0, bh, sacc[0][lt], 0, 0, 0);
            sacc[1][lt] = __builtin_amdgcn_mfma_f32_16x16x32_bf16(ah1, bh, sacc[1][lt], 0, 0, 0);
            sacc[1][lt] = __builtin_amdgcn_mfma_f32_16x16x32_bf16(ah1, bl, sacc[1][lt], 0, 0, 0);
            sacc[1][lt] = __builtin_amdgcn_mfma_f32_16x16x32_bf16(al1, bh, sacc[1][lt], 0, 0, 0);
        }
    }

    // ---- phase B: one softmax pass. lane holds S[n = nt*16+quad*4+r][l = wave*128+lt*16+l16]
    float m[2][4];
#pragma unroll
    for (int nt = 0; nt < 2; ++nt)
#pragma unroll
        for (int r = 0; r < 4; ++r) {
            float v = sacc[nt][0][r];
#pragma unroll
            for (int lt = 1; lt < 8; ++lt) v = fmaxf(v, sacc[nt][lt][r]);
            v = fmaxf(v, __shfl_xor(v, 1));
            v = fmaxf(v, __shfl_xor(v, 2));
            v = fmaxf(v, __shfl_xor(v, 4));
            v = fmaxf(v, __shfl_xor(v, 8));
            m[nt][r] = v;
        }
    if (l16 == 0) {
#pragma unroll
        for (int nt = 0; nt < 2; ++nt)
#pragma unroll
            for (int r = 0; r < 4; ++r) wavemax[wave][nt * 16 + quad * 4 + r] = m[nt][r];
    }
    __syncthreads();
    float dsum[2][4];
#pragma unroll
    for (int nt = 0; nt < 2; ++nt)
#pragma unroll
        for (int r = 0; r < 4; ++r) {
            const int n = nt * 16 + quad * 4 + r;
            m[nt][r] = fmaxf(fmaxf(wavemax[0][n], wavemax[1][n]),
                             fmaxf(wavemax[2][n], wavemax[3][n]));
            float s = 0.f;
#pragma unroll
            for (int lt = 0; lt < 8; ++lt) {
                const float p = __expf(sacc[nt][lt][r] - m[nt][r]);
                s += p;
                Ps[n][wave * 128 + lt * 16 + l16] = (__bf16)p;
            }
            s += __shfl_xor(s, 1);
            s += __shfl_xor(s, 2);
            s += __shfl_xor(s, 4);
            s += __shfl_xor(s, 8);
            dsum[nt][r] = s;
        }
    if (l16 == 0) {
#pragma unroll
        for (int nt = 0; nt < 2; ++nt)
#pragma unroll
            for (int r = 0; r < 4; ++r) wavesum[wave][nt * 16 + quad * 4 + r] = dsum[nt][r];
    }
    __syncthreads();
    float dinv[2][4];
#pragma unroll
    for (int nt = 0; nt < 2; ++nt)
#pragma unroll
        for (int r = 0; r < 4; ++r) {
            const int n = nt * 16 + quad * 4 + r;
            dinv[nt][r] = 1.0f / (wavesum[0][n] + wavesum[1][n] + wavesum[2][n] + wavesum[3][n]);
        }

    // ---- phase C: PV. wave owns f-range wave*128; A=Ps rows(n), B=xT rows(f).
    // Each xT fragment feeds 2 n-tiles.
    f32x4 oacc[2][8];
#pragma unroll
    for (int nt = 0; nt < 2; ++nt)
#pragma unroll
        for (int fs = 0; fs < 8; ++fs) oacc[nt][fs] = (f32x4){0.f, 0.f, 0.f, 0.f};

    const __bf16* xtb = xT + ((size_t)(b * FEAT + wave * 128 + l16)) * LL + quad * 8;
#pragma unroll 2
    for (int kb = 0; kb < 16; ++kb) {
        const bf16x8 ap0 = *(const bf16x8*)&Ps[l16][kb * 32 + quad * 8];
        const bf16x8 ap1 = *(const bf16x8*)&Ps[16 + l16][kb * 32 + quad * 8];
#pragma unroll
        for (int fs = 0; fs < 8; ++fs) {
            const bf16x8 bfrag = *(const bf16x8*)(xtb + (size_t)fs * 16 * LL + kb * 32);
            oacc[0][fs] = __builtin_amdgcn_mfma_f32_16x16x32_bf16(ap0, bfrag, oacc[0][fs], 0, 0, 0);
            oacc[1][fs] = __builtin_amdgcn_mfma_f32_16x16x32_bf16(ap1, bfrag, oacc[1][fs], 0, 0, 0);
        }
    }

#pragma unroll
    for (int nt = 0; nt < 2; ++nt)
#pragma unroll
        for (int fs = 0; fs < 8; ++fs) {
#pragma unroll
            for (int r = 0; r < 4; ++r) {
                const int n = n0 + nt * 16 + quad * 4 + r;
                const int f = wave * 128 + fs * 16 + l16;
                out[((size_t)(b * NLAB + n)) * FEAT + f] = oacc[nt][fs][r] * dinv[nt][r];
            }
        }
}

// ---------------------------------------------------------------------------
// Workspace layout (float-slot offsets), peak ~32 MB:
//   [0        .. 1048576)  lr_hi   (4096*512 bf16)
//   [1048576  .. 2097152)  lr_lo
//   [2097152  .. 2424832)  wB_hi   (16*10*128*4 chunks bf16, dead after conv)
//   [2424832  .. 2752512)  wB_lo   (dead after conv_mfma)
//   [2752512  .. 2752516)  zbuf    (16B zeros, dead after conv_mfma)
//   [2752528  .. 4849680)  lr0     (fp32, dead after linear_kernel)
//   [2097152  .. 4194304)  x_hi    (written by split_x, after linear)
//   [4194304  .. 6291456)  x_lo
//   [6291456  .. 8388608)  xT
// ---------------------------------------------------------------------------
extern "C" void kernel_launch(void* const* d_in, const int* in_sizes, int n_in,
                              void* d_out, int out_size, void* d_ws, size_t ws_size,
                              hipStream_t stream) {
    const float* x          = (const float*)d_in[0];  // (16,512,512)
    const float* label_reps = (const float*)d_in[1];  // (4096,32,300)
    const float* conv_w     = (const float*)d_in[2];  // (512,300,4)
    const float* conv_b     = (const float*)d_in[3];  // (512,)
    const float* lin_w      = (const float*)d_in[4];  // (512,512)
    const float* lin_b      = (const float*)d_in[5];  // (512,)
    float* out = (float*)d_out;

    float* wsf = (float*)d_ws;
    __bf16* lr_hi = (__bf16*)(wsf);
    __bf16* lr_lo = (__bf16*)(wsf + 1048576);
    __bf16* wB_hi = (__bf16*)(wsf + 2097152);
    __bf16* wB_lo = (__bf16*)(wsf + 2424832);
    float*  zbuf  = wsf + 2752512;
    float*  lr0   = wsf + 2752528;
    __bf16* x_hi  = (__bf16*)(wsf + 2097152);   // aliases wB/zbuf/lr0 (dead by then)
    __bf16* x_lo  = (__bf16*)(wsf + 4194304);
    __bf16* xT    = (__bf16*)(wsf + 6291456);

    wprep<<<dim3(320), dim3(256), 0, stream>>>(conv_w, wB_hi, wB_lo, zbuf);
    conv_mfma<<<dim3(16, 1024), dim3(256), 0, stream>>>(label_reps, wB_hi, wB_lo, zbuf, conv_b, lr0);
    linear_kernel<<<dim3(64, 8), dim3(256), 0, stream>>>(lr0, lin_w, lin_b, lr_hi, lr_lo);
    split_x<<<dim3(8, 8, 16), dim3(256), 0, stream>>>(x, x_hi, x_lo, xT);
    attention_mfma<<<dim3(NLAB / 32, BB), dim3(256), 0, stream>>>(x_hi, x_lo, xT, lr_hi, lr_lo, out);
}